// Round 3
// baseline (396.769 us; speedup 1.0000x reference)
//
#include <hip/hip_runtime.h>
#include <hip/hip_bf16.h>
#include <cstdint>

#define NB 256
#define NF 1024
#define NDOF 64
#define NCLS 1000
#define CTILE 128
#define FGROUP 32
#define NFB (NF / FGROUP)            /* 32 f-blocks = partial slices */

typedef __attribute__((ext_vector_type(8))) short short8;
typedef __attribute__((ext_vector_type(16))) float floatx16;

static __device__ inline unsigned short bfu(float f) {   // RNE f32->bf16 via HW cvt
    __hip_bfloat16 h = __float2bfloat16(f);
    union { __hip_bfloat16 h; unsigned short u; } cv;
    cv.h = h;
    return cv.u;
}

// ---------------- Main: per f, partial += V_f (256x64, 2 nz/row) @ W_f^T via
// bf16 MFMA. Block = 512 thr (8 waves): wave w owns b-rows [32w,32w+32),
// CTILE=128 classes (4 MFMA c-subtiles). Grid = 32 x 8 = 256 blocks = 1/CU.
//
// Fused meta: block computes its own {P0 = bf(wA)|bf(wB)<<16, t} for all
// 256 b x 32 f from x at start (x is 1 MB -> L3-resident; 8x redundancy is
// cheap) into padded LDS arrays -> no meta kernel, no meta HBM round-trip.
//
// B tile LDS: linear [128 rows][64 bf16] (128 B rows) with 16 B-granule XOR
// swizzle g ^= (row&7). Both ds_write_b128 (commit) and ds_read_b128 (frags)
// then put 8 distinct-address accesses on each 4-bank group = 128 B/cyc
// optimal, replacing the old even-bank-only b64 pairs (~4-way conflict, 2x
// instruction count).
__global__ __launch_bounds__(512, 2) void lagr_main(
    const float* __restrict__ x, const float* __restrict__ mnp,
    const float* __restrict__ mxp, const float* __restrict__ W,
    float* __restrict__ part)
{
    __shared__ unsigned short wt[2][128 * 64];       // 2 x 16 KB, swizzled
    __shared__ uint32_t mP0[FGROUP][NB + 1];         // +1 pad: conflict-free
    __shared__ uint8_t  mT [FGROUP][NB + 8];
    __shared__ float bias_s[CTILE];

    int tid  = threadIdx.x;
    int lane = tid & 63;
    int wave = tid >> 6;
    int hf   = lane >> 5;                // k-half (granule parity)
    int half8 = hf << 3;
    int l7   = lane & 7;
    int c0 = blockIdx.y * CTILE;
    int f0 = blockIdx.x * FGROUP;

    float mn = mnp[0], mx = mxp[0];
    float scale = mx - mn;
    float inv = 63.0f / scale;

    // staging roles: 4 threads per class row, 16 floats (64 B contiguous) each
    int cst = tid >> 2;
    int q4  = tid & 3;
    int r7w = cst & 7;                   // writer-side swizzle key
    int crow = c0 + cst;
    if (crow > NCLS - 1) crow = NCLS - 1;
    const float* wrow = W + (size_t)crow * (NF * NDOF);

    floatx16 acc0, acc1, acc2, acc3;
#pragma unroll
    for (int r = 0; r < 16; ++r) { acc0[r] = 0.0f; acc1[r] = 0.0f; acc2[r] = 0.0f; acc3[r] = 0.0f; }
    float rowsum = 0.0f;

    float4 st[4];
    auto issue = [&](int f) {
        const float4* src = (const float4*)(wrow + ((size_t)f << 6)) + (q4 << 2);
        st[0] = src[0];
        st[1] = src[1];
        st[2] = src[2];
        st[3] = src[3];
    };
    auto commit = [&](unsigned short* buf) {
        float v[16] = { st[0].x, st[0].y, st[0].z, st[0].w,
                        st[1].x, st[1].y, st[1].z, st[1].w,
                        st[2].x, st[2].y, st[2].z, st[2].w,
                        st[3].x, st[3].y, st[3].z, st[3].w };
        uint32_t d[8];
#pragma unroll
        for (int i = 0; i < 8; ++i) {
            rowsum += v[2 * i] + v[2 * i + 1];
            d[i] = (uint32_t)bfu(v[2 * i]) | ((uint32_t)bfu(v[2 * i + 1]) << 16);
        }
        unsigned short* row = buf + cst * 64;
        // granules 2q4, 2q4+1, XOR-swizzled; 16 B-aligned ds_write_b128 x2
        *(uint4*)(row + (((2 * q4)     ^ r7w) << 3)) = make_uint4(d[0], d[1], d[2], d[3]);
        *(uint4*)(row + (((2 * q4 + 1) ^ r7w) << 3)) = make_uint4(d[4], d[5], d[6], d[7]);
    };

    unsigned short* cur = &wt[0][0];
    unsigned short* nxt = &wt[1][0];

    issue(f0);                                        // W prefetch first

    // ---- fused meta: lanes 0..31 of each half-wave read 128 B of one x row
    {
        int fl = tid & 31, bq = tid >> 5;
#pragma unroll
        for (int i = 0; i < 16; ++i) {
            int b = bq + i * 16;
            float xv = x[(size_t)b * NF + f0 + fl];
            float s = (xv - mn) * inv;
            float wA = 0.0f, wB = 0.0f;
            uint32_t t = 0u;
            if (s >= 0.0f && s <= 63.0f) {
                float tf = floorf(s);
                if (tf > 62.0f) tf = 62.0f;
                t  = (uint32_t)tf;
                wA = scale * (tf + 1.0f - s);
                wB = scale * (s - tf);
            }
            mP0[fl][b] = (uint32_t)bfu(wA) | ((uint32_t)bfu(wB) << 16);
            mT[fl][b]  = (uint8_t)t;
        }
    }

    commit(cur);
    __syncthreads();

    int mb = wave * 32 + (lane & 31);    // this lane's b-row (A row m)

#pragma unroll 1
    for (int ch = 0; ch < FGROUP; ++ch) {
        int f = f0 + ch;
        bool more = (ch + 1 < FGROUP);
        if (more) issue(f + 1);                        // prefetch next W chunk

        // ---- A-frags from LDS meta (parity trick): pair base k0 always even,
        // (t,t+1) lands in ONE slot (t even) or TWO adjacent slots (t odd).
        uint32_t P0 = mP0[ch][mb];
        uint32_t t  = mT[ch][mb];
        uint32_t odd = t & 1u;
        uint32_t X0 = odd ? (P0 << 16) : P0;
        uint32_t X1 = odd ? (P0 >> 16) : 0u;
        int d0 = (int)(t & ~1u) - half8;

        short8 afrag[4];
#pragma unroll
        for (int kc = 0; kc < 4; ++kc) {
            union { uint32_t u[4]; short8 v; } a;
#pragma unroll
            for (int q = 0; q < 4; ++q) {
                int C = kc * 16 + 2 * q;   // even pair-base (relative to half8)
                a.u[q] = (d0 == C) ? X0 : (d0 == C - 2) ? X1 : 0u;
            }
            afrag[kc] = a.v;
        }

        // ---- B-frags: one swizzled ds_read_b128 each + MFMA (4 c-subtiles)
#define CTBODY(CT, ACC) { \
        const unsigned short* rrow = cur + (size_t)((lane & 31) + 32 * (CT)) * 64; \
        _Pragma("unroll") \
        for (int kc = 0; kc < 4; ++kc) { \
            short8 bv = *(const short8*)(rrow + (((2 * kc + hf) ^ l7) << 3)); \
            ACC = __builtin_amdgcn_mfma_f32_32x32x16_bf16(afrag[kc], bv, ACC, 0, 0, 0); \
        } }
        CTBODY(0, acc0)
        CTBODY(1, acc1)
        CTBODY(2, acc2)
        CTBODY(3, acc3)
#undef CTBODY

        if (more) commit(nxt);
        unsigned short* tmp = cur; cur = nxt; nxt = tmp;
        __syncthreads();
    }

    // ---- bias = min_x * sum_k W[c,k] over this block's f-range
    rowsum += __shfl_xor(rowsum, 1);
    rowsum += __shfl_xor(rowsum, 2);
    if (q4 == 0) bias_s[cst] = mn * rowsum;
    __syncthreads();

    // ---- epilogue: plain coalesced stores into this f-block's partial slice.
    // C/D layout col=lane&31, row=(reg&3)+8*(reg>>2)+4*(lane>>5)
    float* pslice = part + (size_t)blockIdx.x * NB * NCLS;
    int col = lane & 31;
    int rowhi = hf << 2;
#define EPI(CT, ACC) { \
        int c = c0 + (CT) * 32 + col; \
        if (c < NCLS) { \
            float bias = bias_s[(CT) * 32 + col]; \
            _Pragma("unroll") \
            for (int r = 0; r < 16; ++r) { \
                int brow = (r & 3) + 8 * (r >> 2) + rowhi; \
                pslice[(size_t)(wave * 32 + brow) * NCLS + c] = ACC[r] + bias; \
            } } }
    EPI(0, acc0)
    EPI(1, acc1)
    EPI(2, acc2)
    EPI(3, acc3)
#undef EPI
}

// ---------------- Reduce: out[b][c] = sum_fb part[fb][b][c].
// Flat float4 over 256000 floats; 4 independent accumulator chains for ILP.
__global__ __launch_bounds__(256) void lagr_reduce(
    const float* __restrict__ part, float* __restrict__ out)
{
    int i = blockIdx.x * blockDim.x + threadIdx.x;     // float4 index, < 64000
    const float4* p = (const float4*)part;
    float4 a0 = make_float4(0.f, 0.f, 0.f, 0.f), a1 = a0, a2 = a0, a3 = a0;
    const int S = NB * NCLS / 4;                       // float4 stride per slice
#pragma unroll
    for (int fb = 0; fb < NFB; fb += 4) {
        float4 v0 = p[(size_t)(fb + 0) * S + i];
        float4 v1 = p[(size_t)(fb + 1) * S + i];
        float4 v2 = p[(size_t)(fb + 2) * S + i];
        float4 v3 = p[(size_t)(fb + 3) * S + i];
        a0.x += v0.x; a0.y += v0.y; a0.z += v0.z; a0.w += v0.w;
        a1.x += v1.x; a1.y += v1.y; a1.z += v1.z; a1.w += v1.w;
        a2.x += v2.x; a2.y += v2.y; a2.z += v2.z; a2.w += v2.w;
        a3.x += v3.x; a3.y += v3.y; a3.z += v3.z; a3.w += v3.w;
    }
    float4 r;
    r.x = (a0.x + a1.x) + (a2.x + a3.x);
    r.y = (a0.y + a1.y) + (a2.y + a3.y);
    r.z = (a0.z + a1.z) + (a2.z + a3.z);
    r.w = (a0.w + a1.w) + (a2.w + a3.w);
    ((float4*)out)[i] = r;
}

extern "C" void kernel_launch(void* const* d_in, const int* in_sizes, int n_in,
                              void* d_out, int out_size, void* d_ws, size_t ws_size,
                              hipStream_t stream) {
    const float* x  = (const float*)d_in[0];
    const float* mn = (const float*)d_in[1];
    const float* mx = (const float*)d_in[2];
    const float* W  = (const float*)d_in[3];
    float* out = (float*)d_out;
    float* part = (float*)d_ws;          // 32 f-slices x 256 x 1000 fp32 = 32.8 MB

    dim3 grid(NF / FGROUP, (NCLS + CTILE - 1) / CTILE);
    lagr_main<<<grid, dim3(512), 0, stream>>>(x, mn, mx, W, part);

    lagr_reduce<<<dim3(NB * NCLS / 4 / 256), dim3(256), 0, stream>>>(part, out);
}

// Round 4
// 381.151 us; speedup vs baseline: 1.0410x; 1.0410x over previous
//
#include <hip/hip_runtime.h>
#include <hip/hip_bf16.h>
#include <cstdint>

#define NB 256
#define NF 1024
#define NDOF 64
#define NCLS 1000
#define CTILE 128
#define FGROUP 32
#define NFB (NF / FGROUP)            /* 32 f-blocks = partial slices */
#define SUBSZ (128 * 64)             /* shorts per B sub-tile */

typedef __attribute__((ext_vector_type(8))) short short8;
typedef __attribute__((ext_vector_type(16))) float floatx16;

static __device__ inline unsigned short bfu(float f) {   // RNE f32->bf16 via HW cvt
    __hip_bfloat16 h = __float2bfloat16(f);
    union { __hip_bfloat16 h; unsigned short u; } cv;
    cv.h = h;
    return cv.u;
}

// ---------------- Phase 1: meta[f][b] = {P0 = bf(wA) | bf(wB)<<16, t}.
// wA = (mx-mn)*lam1 @ vertex t, wB = (mx-mn)*lam0 @ vertex t+1.
// 32x32 LDS transpose tiles: coalesced x reads AND coalesced meta writes.
__global__ __launch_bounds__(256) void lagr_meta(
    const float* __restrict__ x, const float* __restrict__ mnp,
    const float* __restrict__ mxp, uint2* __restrict__ meta)
{
    __shared__ uint2 tile[32][33];
    int f0 = blockIdx.x * 32;
    int b0 = blockIdx.y * 32;
    int tid = threadIdx.x;
    float mn = mnp[0], mx = mxp[0];
    float scale = mx - mn;
    float inv = 63.0f / scale;

    int fl = tid & 31, br = tid >> 5;
#pragma unroll
    for (int i = 0; i < 4; ++i) {
        int bl = br + i * 8;
        float xv = x[(size_t)(b0 + bl) * NF + f0 + fl];
        float s = (xv - mn) * inv;
        float wA = 0.0f, wB = 0.0f;
        uint32_t t = 0u;
        if (s >= 0.0f && s <= 63.0f) {
            float tf = floorf(s);
            if (tf > 62.0f) tf = 62.0f;
            t  = (uint32_t)tf;
            wA = scale * (tf + 1.0f - s);
            wB = scale * (s - tf);
        }
        uint32_t P0 = (uint32_t)bfu(wA) | ((uint32_t)bfu(wB) << 16);
        tile[fl][bl] = make_uint2(P0, t);
    }
    __syncthreads();
    int bl = tid & 31, fr = tid >> 5;
#pragma unroll
    for (int i = 0; i < 4; ++i) {
        int f = fr + i * 8;
        meta[(size_t)(f0 + f) * NB + b0 + bl] = tile[f][bl];
    }
}

// ---------------- Phase 2: per f, partial += V_f (256x64, 2 nz/row) @ W_f^T
// via bf16 MFMA. Block = 512 thr (8 waves): wave w owns b-rows [32w,32w+32),
// CTILE=128 classes (4 MFMA c-subtiles). Grid = 32 x 8 = 256 blocks = 1/CU.
// TWO f-chunks per pipeline step: 16 barriers instead of 32; staging is one
// 512 B contiguous read per class row per step (4 thr x 128 B).
// B sub-tile LDS: linear [128 rows][64 bf16] with 16 B-granule XOR swizzle
// g ^= (row&7); writer (ds_write_b128 x4) and reader (ds_read_b128) use the
// same involution -> single-instruction fragments, even bank spread.
// NO ATOMICS: each f-block writes partial slice part[fb][b][c] (bias folded);
// reduce kernel sums the 32 slices.
__global__ __launch_bounds__(512, 2) void lagr_main(
    const uint2* __restrict__ meta, const float* __restrict__ W,
    const float* __restrict__ mnp, float* __restrict__ part)
{
    __shared__ unsigned short wt[2][2][SUBSZ];   // [buf][sub]: 64 KB
    __shared__ float bias_s[CTILE];

    int tid  = threadIdx.x;
    int lane = tid & 63;
    int wave = tid >> 6;
    int hf   = lane >> 5;                // k-half (granule parity)
    int half8 = hf << 3;
    int l7   = lane & 7;
    int c0 = blockIdx.y * CTILE;
    int f0 = blockIdx.x * FGROUP;

    // staging roles: 4 threads per class row, 128 B contiguous each (512 B/row
    // per step = chunks f and f+1 back-to-back)
    int cst = tid >> 2;
    int q4  = tid & 3;
    int r7w = cst & 7;                   // writer-side swizzle key
    int sub = q4 >> 1;                   // which sub-tile this thread commits
    int gb  = (q4 & 1) << 2;             // base granule within sub row
    int crow = c0 + cst;
    if (crow > NCLS - 1) crow = NCLS - 1;
    const float* wrow = W + (size_t)crow * (NF * NDOF);

    floatx16 acc0, acc1, acc2, acc3;
#pragma unroll
    for (int r = 0; r < 16; ++r) { acc0[r] = 0.0f; acc1[r] = 0.0f; acc2[r] = 0.0f; acc3[r] = 0.0f; }
    float rowsum = 0.0f;

    float4 st[8];
    auto issue2 = [&](int f) {           // stage chunks f, f+1 (contiguous)
        const float4* src = (const float4*)(wrow + ((size_t)f << 6)) + (q4 << 3);
#pragma unroll
        for (int i = 0; i < 8; ++i) st[i] = src[i];
    };
    auto commit2 = [&](unsigned short* buf) {   // buf -> wt[b][0]
        float v[32];
#pragma unroll
        for (int i = 0; i < 8; ++i) {
            v[4 * i + 0] = st[i].x; v[4 * i + 1] = st[i].y;
            v[4 * i + 2] = st[i].z; v[4 * i + 3] = st[i].w;
        }
        uint32_t d[16];
#pragma unroll
        for (int i = 0; i < 16; ++i) {
            rowsum += v[2 * i] + v[2 * i + 1];
            d[i] = (uint32_t)bfu(v[2 * i]) | ((uint32_t)bfu(v[2 * i + 1]) << 16);
        }
        // thread q4 holds granules gb..gb+3 of sub-tile `sub`, row cst
        unsigned short* row = buf + sub * SUBSZ + cst * 64;
#pragma unroll
        for (int g = 0; g < 4; ++g)
            *(uint4*)(row + (((gb + g) ^ r7w) << 3)) =
                make_uint4(d[4 * g], d[4 * g + 1], d[4 * g + 2], d[4 * g + 3]);
    };

    unsigned short* cur = &wt[0][0][0];
    unsigned short* nxt = &wt[1][0][0];

    // this lane's b-row (A row m = lane&31); both half-waves share the same b
    const uint2* mbase = meta + wave * 32 + (lane & 31);
    uint2 m0 = mbase[(size_t)(f0 + 0) * NB];
    uint2 m1 = mbase[(size_t)(f0 + 1) * NB];

    issue2(f0);
    commit2(cur);
    __syncthreads();

#pragma unroll 1
    for (int g = 0; g < FGROUP / 2; ++g) {
        int f = f0 + 2 * g;
        bool more = (g + 1 < FGROUP / 2);
        if (more) issue2(f + 2);                       // prefetch next W pair
        uint2 n0 = m0, n1 = m1;
        if (more) {
            n0 = mbase[(size_t)(f + 2) * NB];          // prefetch next meta pair
            n1 = mbase[(size_t)(f + 3) * NB];
        }

        // ---- A-frags (parity trick): pair base k0 always even, (t,t+1) lands
        // in ONE slot (t even) or TWO adjacent slots (t odd).
#define ABUILD(M, AF) { \
        uint32_t P0 = (M).x; \
        uint32_t t  = (M).y; \
        uint32_t odd = t & 1u; \
        uint32_t X0 = odd ? (P0 << 16) : P0; \
        uint32_t X1 = odd ? (P0 >> 16) : 0u; \
        int d0 = (int)(t & ~1u) - half8; \
        _Pragma("unroll") \
        for (int kc = 0; kc < 4; ++kc) { \
            union { uint32_t u[4]; short8 v; } a; \
            _Pragma("unroll") \
            for (int q = 0; q < 4; ++q) { \
                int C = kc * 16 + 2 * q; \
                a.u[q] = (d0 == C) ? X0 : (d0 == C - 2) ? X1 : 0u; \
            } \
            AF[kc] = a.v; \
        } }
        short8 af0[4], af1[4];
        ABUILD(m0, af0)
        ABUILD(m1, af1)
#undef ABUILD

        // ---- B-frags: one swizzled ds_read_b128 each + MFMA (4 c-subtiles x
        // 2 sub-chunks)
#define CTBODY(SUB, AF, CT, ACC) { \
        const unsigned short* rrow = cur + (SUB) * SUBSZ + (size_t)((lane & 31) + 32 * (CT)) * 64; \
        _Pragma("unroll") \
        for (int kc = 0; kc < 4; ++kc) { \
            short8 bv = *(const short8*)(rrow + (((2 * kc + hf) ^ l7) << 3)); \
            ACC = __builtin_amdgcn_mfma_f32_32x32x16_bf16(AF[kc], bv, ACC, 0, 0, 0); \
        } }
        CTBODY(0, af0, 0, acc0)
        CTBODY(0, af0, 1, acc1)
        CTBODY(0, af0, 2, acc2)
        CTBODY(0, af0, 3, acc3)
        CTBODY(1, af1, 0, acc0)
        CTBODY(1, af1, 1, acc1)
        CTBODY(1, af1, 2, acc2)
        CTBODY(1, af1, 3, acc3)
#undef CTBODY

        if (more) commit2(nxt);
        unsigned short* tmp = cur; cur = nxt; nxt = tmp;
        m0 = n0; m1 = n1;
        __syncthreads();
    }

    // ---- bias = min_x * sum_k W[c,k] over this block's f-range
    rowsum += __shfl_xor(rowsum, 1);
    rowsum += __shfl_xor(rowsum, 2);
    if (q4 == 0) bias_s[cst] = mnp[0] * rowsum;
    __syncthreads();

    // ---- epilogue: plain coalesced stores into this f-block's partial slice.
    // C/D layout col=lane&31, row=(reg&3)+8*(reg>>2)+4*(lane>>5)
    float* pslice = part + (size_t)blockIdx.x * NB * NCLS;
    int col = lane & 31;
    int rowhi = hf << 2;
#define EPI(CT, ACC) { \
        int c = c0 + (CT) * 32 + col; \
        if (c < NCLS) { \
            float bias = bias_s[(CT) * 32 + col]; \
            _Pragma("unroll") \
            for (int r = 0; r < 16; ++r) { \
                int brow = (r & 3) + 8 * (r >> 2) + rowhi; \
                pslice[(size_t)(wave * 32 + brow) * NCLS + c] = ACC[r] + bias; \
            } } }
    EPI(0, acc0)
    EPI(1, acc1)
    EPI(2, acc2)
    EPI(3, acc3)
#undef EPI
}

// ---------------- Phase 3: out[b][c] = sum_fb part[fb][b][c].
// Flat float4 over 256000 floats; 4 independent accumulator chains for ILP.
__global__ __launch_bounds__(256) void lagr_reduce(
    const float* __restrict__ part, float* __restrict__ out)
{
    int i = blockIdx.x * blockDim.x + threadIdx.x;     // float4 index, < 64000
    const float4* p = (const float4*)part;
    float4 a0 = make_float4(0.f, 0.f, 0.f, 0.f), a1 = a0, a2 = a0, a3 = a0;
    const int S = NB * NCLS / 4;                       // float4 stride per slice
#pragma unroll
    for (int fb = 0; fb < NFB; fb += 4) {
        float4 v0 = p[(size_t)(fb + 0) * S + i];
        float4 v1 = p[(size_t)(fb + 1) * S + i];
        float4 v2 = p[(size_t)(fb + 2) * S + i];
        float4 v3 = p[(size_t)(fb + 3) * S + i];
        a0.x += v0.x; a0.y += v0.y; a0.z += v0.z; a0.w += v0.w;
        a1.x += v1.x; a1.y += v1.y; a1.z += v1.z; a1.w += v1.w;
        a2.x += v2.x; a2.y += v2.y; a2.z += v2.z; a2.w += v2.w;
        a3.x += v3.x; a3.y += v3.y; a3.z += v3.z; a3.w += v3.w;
    }
    float4 r;
    r.x = (a0.x + a1.x) + (a2.x + a3.x);
    r.y = (a0.y + a1.y) + (a2.y + a3.y);
    r.z = (a0.z + a1.z) + (a2.z + a3.z);
    r.w = (a0.w + a1.w) + (a2.w + a3.w);
    ((float4*)out)[i] = r;
}

extern "C" void kernel_launch(void* const* d_in, const int* in_sizes, int n_in,
                              void* d_out, int out_size, void* d_ws, size_t ws_size,
                              hipStream_t stream) {
    const float* x  = (const float*)d_in[0];
    const float* mn = (const float*)d_in[1];
    const float* mx = (const float*)d_in[2];
    const float* W  = (const float*)d_in[3];
    float* out = (float*)d_out;
    uint2* meta = (uint2*)d_ws;                               // 2 MB
    float* part = (float*)((char*)d_ws + (size_t)NF * NB * 8); // 32.8 MB partials

    lagr_meta<<<dim3(NF / 32, NB / 32), dim3(256), 0, stream>>>(x, mn, mx, meta);

    dim3 grid(NF / FGROUP, (NCLS + CTILE - 1) / CTILE);
    lagr_main<<<grid, dim3(512), 0, stream>>>(meta, W, mn, part);

    lagr_reduce<<<dim3(NB * NCLS / 4 / 256), dim3(256), 0, stream>>>(part, out);
}